// Round 9
// baseline (75.637 us; speedup 1.0000x reference)
//
#include <hip/hip_runtime.h>

// MLPPredictor: score[e] = concat(nfeats[src[e]], nfeats[dst[e]], efeats[e]) @ W^T + b
// E = 625000, N = 100000, D = 128, OUT = 2.
//
// Two-kernel affine split:
//   p[n] = (n@W0s, n@W1s, n@W0d, n@W1d)  -> float4 table (1.6 MB, L2-resident)
//   score[e] = efeats[e]@We + p[src].xy + p[dst].zw + b
//
// Edge kernel: 8 edges / 32-lane group / iteration, fold-reduction (16 chains,
// 16 shuffles), distance-2 register pipeline (heA/heB). Grid = 1024 blocks
// (fully co-resident; ~10 steady-state batches per block).
// Node kernel: 4 nodes / group / iteration (16 chains, same fold), dist-1
// pipeline, coalesced 64 B pf stores (normal stores: edge re-reads via L2).

static constexpr int D = 128;
static constexpr int THREADS = 256;
static constexpr int GPB = THREADS / 32;  // 32-lane groups per block

typedef float f32x4 __attribute__((ext_vector_type(4)));

__device__ __forceinline__ void load_batch(f32x4 (&he)[8], const float* __restrict__ efeats,
                                           int e, int sl) {
    #pragma unroll
    for (int j = 0; j < 8; ++j)
        he[j] = __builtin_nontemporal_load(
            reinterpret_cast<const f32x4*>(efeats + (size_t)(e + j) * D + 4 * sl));
}

__device__ __forceinline__ void fma_batch(float (&v)[16], const f32x4 (&he)[8],
                                          const float4& w0e, const float4& w1e) {
    #pragma unroll
    for (int j = 0; j < 8; ++j) {
        v[2*j]   = he[j].x * w0e.x + he[j].y * w0e.y + he[j].z * w0e.z + he[j].w * w0e.w;
        v[2*j+1] = he[j].x * w1e.x + he[j].y * w1e.y + he[j].z * w1e.z + he[j].w * w1e.w;
    }
}

// fold 16 chains across 32 lanes: after this, even lane sl holds chain sl>>1
__device__ __forceinline__ float fold16(const float (&v)[16], int sl) {
    float a8[8];
    #pragma unroll
    for (int c = 0; c < 8; ++c) {
        float send = (sl & 16) ? v[c] : v[c+8];
        float keep = (sl & 16) ? v[c+8] : v[c];
        a8[c] = keep + __shfl_xor(send, 16);
    }
    float a4[4];
    #pragma unroll
    for (int c = 0; c < 4; ++c) {
        float send = (sl & 8) ? a8[c] : a8[c+4];
        float keep = (sl & 8) ? a8[c+4] : a8[c];
        a4[c] = keep + __shfl_xor(send, 8);
    }
    float a2[2];
    #pragma unroll
    for (int c = 0; c < 2; ++c) {
        float send = (sl & 4) ? a4[c] : a4[c+2];
        float keep = (sl & 4) ? a4[c+2] : a4[c];
        a2[c] = keep + __shfl_xor(send, 4);
    }
    float y;
    {
        float send = (sl & 2) ? a2[0] : a2[1];
        float keep = (sl & 2) ? a2[1] : a2[0];
        y = keep + __shfl_xor(send, 2);
    }
    y += __shfl_xor(y, 1);
    return y;
}

// ---------- kernel 1: per-node partials (4 nodes/group, fold, dist-1 pipeline) ----------
__global__ __launch_bounds__(THREADS) void node_partial_kernel(
    const float* __restrict__ nfeats,   // [N, 128]
    const float* __restrict__ W,        // [2, 384]
    float*       __restrict__ pf,       // [N*4] (s0, s1, d0, d1) per node
    int N)
{
    const int sl   = threadIdx.x & 31;
    const int gib  = threadIdx.x >> 5;
    const int g0   = blockIdx.x * GPB + gib;
    const int ngrp = gridDim.x * GPB;
    const int nstep = ngrp * 4;

    const float4 w0s = *reinterpret_cast<const float4*>(W +   0 + 4 * sl);
    const float4 w1s = *reinterpret_cast<const float4*>(W + 384 + 4 * sl);
    const float4 w0d = *reinterpret_cast<const float4*>(W + 128 + 4 * sl);
    const float4 w1d = *reinterpret_cast<const float4*>(W + 384 + 128 + 4 * sl);

    int n = g0 * 4;
    if (n + 3 >= N) return;

    f32x4 h[4];
    #pragma unroll
    for (int j = 0; j < 4; ++j)
        h[j] = __builtin_nontemporal_load(
            reinterpret_cast<const f32x4*>(nfeats + (size_t)(n + j) * D + 4 * sl));

    while (n + 3 < N) {
        // chains c = j*4 + k  (j = node 0..3, k = comp s0,s1,d0,d1)
        float v[16];
        #pragma unroll
        for (int j = 0; j < 4; ++j) {
            v[j*4+0] = h[j].x * w0s.x + h[j].y * w0s.y + h[j].z * w0s.z + h[j].w * w0s.w;
            v[j*4+1] = h[j].x * w1s.x + h[j].y * w1s.y + h[j].z * w1s.z + h[j].w * w1s.w;
            v[j*4+2] = h[j].x * w0d.x + h[j].y * w0d.y + h[j].z * w0d.z + h[j].w * w0d.w;
            v[j*4+3] = h[j].x * w1d.x + h[j].y * w1d.y + h[j].z * w1d.z + h[j].w * w1d.w;
        }

        const int nn = n + nstep;
        if (nn + 3 < N) {
            #pragma unroll
            for (int j = 0; j < 4; ++j)
                h[j] = __builtin_nontemporal_load(
                    reinterpret_cast<const f32x4*>(nfeats + (size_t)(nn + j) * D + 4 * sl));
        }

        const float y = fold16(v, sl);
        // even lane sl holds chain c = sl>>1; pf[4n + c] -> 64 B coalesced,
        // NORMAL store (edge kernel re-reads this table through L2)
        if ((sl & 1) == 0) {
            pf[4 * (size_t)n + (sl >> 1)] = y;
        }
        n = nn;
    }
}

// ---------- kernel 2: distance-2 pipelined edge kernel (8 edges/group) ----------
__global__ __launch_bounds__(THREADS) void edge_kernel(
    const float*  __restrict__ efeats,  // [E, 128]
    const int*    __restrict__ src,     // [E]
    const int*    __restrict__ dst,     // [E]
    const float*  __restrict__ W,       // [2, 384]
    const float*  __restrict__ bias,    // [2]
    const float*  __restrict__ pf,      // [N*4]
    float*        __restrict__ out,     // [E, 2]
    int E)
{
    const int sl   = threadIdx.x & 31;
    const int gib  = threadIdx.x >> 5;
    const int g0   = blockIdx.x * GPB + gib;
    const int ngrp = gridDim.x * GPB;
    const int step = ngrp * 8;

    const float4 w0e = *reinterpret_cast<const float4*>(W + 256 + 4 * sl);
    const float4 w1e = *reinterpret_cast<const float4*>(W + 384 + 256 + 4 * sl);

    const bool wr   = (sl & 1) == 0;
    const int  myj  = sl >> 2;          // writer's edge within the 8-batch
    const int  myo  = (sl >> 1) & 1;    // writer's output index
    const float myb = myo ? bias[1] : bias[0];

    int e = g0 * 8;
    if (e + 7 >= E) return;

    // ---- prologue: fill both pipeline stages ----
    f32x4 heA[8], heB[8];
    int sA = 0, dA = 0, sB = 0, dB = 0;

    load_batch(heA, efeats, e, sl);
    if (wr) { sA = src[e + myj]; dA = dst[e + myj]; }
    if (e + step + 7 < E) {
        load_batch(heB, efeats, e + step, sl);
        if (wr) { sB = src[e + step + myj]; dB = dst[e + step + myj]; }
    }

    for (;;) {
        // ---- process batch in A registers (edges e..e+7) ----
        {
            float ps = 0.f, pd = 0.f;
            if (wr) {
                ps = pf[(size_t)sA * 4 + myo];
                pd = pf[(size_t)dA * 4 + 2 + myo];
            }
            float v[16];
            fma_batch(v, heA, w0e, w1e);
            const int ep = e + 2 * step;          // refill A two stages ahead
            if (ep + 7 < E) {
                load_batch(heA, efeats, ep, sl);
                if (wr) { sA = src[ep + myj]; dA = dst[ep + myj]; }
            }
            const float y = fold16(v, sl);
            if (wr)
                __builtin_nontemporal_store(y + ps + pd + myb,
                                            out + 2 * (size_t)e + (sl >> 1));
        }
        e += step;
        if (e + 7 >= E) break;

        // ---- process batch in B registers (edges e..e+7) ----
        {
            float ps = 0.f, pd = 0.f;
            if (wr) {
                ps = pf[(size_t)sB * 4 + myo];
                pd = pf[(size_t)dB * 4 + 2 + myo];
            }
            float v[16];
            fma_batch(v, heB, w0e, w1e);
            const int ep = e + 2 * step;          // refill B two stages ahead
            if (ep + 7 < E) {
                load_batch(heB, efeats, ep, sl);
                if (wr) { sB = src[ep + myj]; dB = dst[ep + myj]; }
            }
            const float y = fold16(v, sl);
            if (wr)
                __builtin_nontemporal_store(y + ps + pd + myb,
                                            out + 2 * (size_t)e + (sl >> 1));
        }
        e += step;
        if (e + 7 >= E) break;
    }
}

// ---------- fallback: single-kernel (if ws too small) ----------
__global__ __launch_bounds__(THREADS) void mlp_pred_fused_kernel(
    const float* __restrict__ nfeats, const float* __restrict__ efeats,
    const int* __restrict__ src, const int* __restrict__ dst,
    const float* __restrict__ W, const float* __restrict__ bias,
    float* __restrict__ out, int E)
{
    const int sl = threadIdx.x & 31;
    const int gib = threadIdx.x >> 5;
    const int g0 = blockIdx.x * GPB + gib;
    const int ngrp = gridDim.x * GPB;

    const float4 w0s = *reinterpret_cast<const float4*>(W +   0 + 4 * sl);
    const float4 w0d = *reinterpret_cast<const float4*>(W + 128 + 4 * sl);
    const float4 w0e = *reinterpret_cast<const float4*>(W + 256 + 4 * sl);
    const float4 w1s = *reinterpret_cast<const float4*>(W + 384 +   0 + 4 * sl);
    const float4 w1d = *reinterpret_cast<const float4*>(W + 384 + 128 + 4 * sl);
    const float4 w1e = *reinterpret_cast<const float4*>(W + 384 + 256 + 4 * sl);
    const float b0 = bias[0];
    const float b1 = bias[1];

    for (int e = g0; e < E; e += ngrp) {
        const int si = src[e];
        const int di = dst[e];
        const float4 hs = *reinterpret_cast<const float4*>(nfeats + (size_t)si * D + 4 * sl);
        const float4 hd = *reinterpret_cast<const float4*>(nfeats + (size_t)di * D + 4 * sl);
        const float4 he = *reinterpret_cast<const float4*>(efeats + (size_t)e  * D + 4 * sl);

        float a0 = hs.x * w0s.x + hs.y * w0s.y + hs.z * w0s.z + hs.w * w0s.w;
        a0 += hd.x * w0d.x + hd.y * w0d.y + hd.z * w0d.z + hd.w * w0d.w;
        a0 += he.x * w0e.x + he.y * w0e.y + he.z * w0e.z + he.w * w0e.w;
        float a1 = hs.x * w1s.x + hs.y * w1s.y + hs.z * w1s.z + hs.w * w1s.w;
        a1 += hd.x * w1d.x + hd.y * w1d.y + hd.z * w1d.z + hd.w * w1d.w;
        a1 += he.x * w1e.x + he.y * w1e.y + he.z * w1e.z + he.w * w1e.w;

        #pragma unroll
        for (int off = 16; off; off >>= 1) {
            a0 += __shfl_xor(a0, off);
            a1 += __shfl_xor(a1, off);
        }
        if (sl == 0)
            *reinterpret_cast<float2*>(out + 2 * (size_t)e) = make_float2(a0 + b0, a1 + b1);
    }
}

extern "C" void kernel_launch(void* const* d_in, const int* in_sizes, int n_in,
                              void* d_out, int out_size, void* d_ws, size_t ws_size,
                              hipStream_t stream) {
    const float* nfeats = (const float*)d_in[0];
    const float* efeats = (const float*)d_in[1];
    const int*   src    = (const int*)d_in[2];
    const int*   dst    = (const int*)d_in[3];
    const float* W      = (const float*)d_in[4];
    const float* bias   = (const float*)d_in[5];
    float*       out    = (float*)d_out;

    const int E = in_sizes[2];
    const int N = in_sizes[0] / D;

    const size_t p_bytes = (size_t)N * 4 * sizeof(float);

    if (ws_size >= p_bytes && (E & 7) == 0 && (N & 3) == 0) {
        float* pf = (float*)d_ws;

        int groups1 = N / 4;
        int blocks1 = (groups1 + GPB - 1) / GPB;
        if (blocks1 > 2048) blocks1 = 2048;
        node_partial_kernel<<<blocks1, THREADS, 0, stream>>>(nfeats, W, pf, N);

        int groups2 = E / 8;
        int blocks2 = (groups2 + GPB - 1) / GPB;
        if (blocks2 > 1024) blocks2 = 1024;   // fully co-resident; ~10 batches/block
        edge_kernel<<<blocks2, THREADS, 0, stream>>>(efeats, src, dst, W, bias, pf, out, E);
    } else {
        int blocks = (E + GPB - 1) / GPB;
        if (blocks > 2048) blocks = 2048;
        mlp_pred_fused_kernel<<<blocks, THREADS, 0, stream>>>(nfeats, efeats, src, dst, W, bias, out, E);
    }
}

// Round 10
// 70.692 us; speedup vs baseline: 1.0699x; 1.0699x over previous
//
#include <hip/hip_runtime.h>

// MLPPredictor: score[e] = concat(nfeats[src[e]], nfeats[dst[e]], efeats[e]) @ W^T + b
// E = 625000, N = 100000, D = 128, OUT = 2.
//
// Two-kernel affine split:
//   p[n] = (n@W0s, n@W1s, n@W0d, n@W1d)  -> float4 table (1.6 MB, L2-resident)
//   score[e] = efeats[e]@We + p[src].xy + p[dst].zw + b
//
// Edge kernel (== round-8 exactly): 8 edges / 32-lane group, fold-reduction
// (16 chains, 16 shuffles), distance-2 register pipeline (heA/heB), grid 2048.
// Node kernel: 4 nodes / group (16 chains, same fold), dist-1 pipeline,
// coalesced 64 B pf stores.

static constexpr int D = 128;
static constexpr int THREADS = 256;
static constexpr int GPB = THREADS / 32;  // 32-lane groups per block

typedef float f32x4 __attribute__((ext_vector_type(4)));

__device__ __forceinline__ void load_batch(f32x4 (&he)[8], const float* __restrict__ efeats,
                                           int e, int sl) {
    #pragma unroll
    for (int j = 0; j < 8; ++j)
        he[j] = __builtin_nontemporal_load(
            reinterpret_cast<const f32x4*>(efeats + (size_t)(e + j) * D + 4 * sl));
}

__device__ __forceinline__ void fma_batch(float (&v)[16], const f32x4 (&he)[8],
                                          const float4& w0e, const float4& w1e) {
    #pragma unroll
    for (int j = 0; j < 8; ++j) {
        v[2*j]   = he[j].x * w0e.x + he[j].y * w0e.y + he[j].z * w0e.z + he[j].w * w0e.w;
        v[2*j+1] = he[j].x * w1e.x + he[j].y * w1e.y + he[j].z * w1e.z + he[j].w * w1e.w;
    }
}

// fold 16 chains across 32 lanes: after this, even lane sl holds chain sl>>1
__device__ __forceinline__ float fold16(const float (&v)[16], int sl) {
    float a8[8];
    #pragma unroll
    for (int c = 0; c < 8; ++c) {
        float send = (sl & 16) ? v[c] : v[c+8];
        float keep = (sl & 16) ? v[c+8] : v[c];
        a8[c] = keep + __shfl_xor(send, 16);
    }
    float a4[4];
    #pragma unroll
    for (int c = 0; c < 4; ++c) {
        float send = (sl & 8) ? a8[c] : a8[c+4];
        float keep = (sl & 8) ? a8[c+4] : a8[c];
        a4[c] = keep + __shfl_xor(send, 8);
    }
    float a2[2];
    #pragma unroll
    for (int c = 0; c < 2; ++c) {
        float send = (sl & 4) ? a4[c] : a4[c+2];
        float keep = (sl & 4) ? a4[c+2] : a4[c];
        a2[c] = keep + __shfl_xor(send, 4);
    }
    float y;
    {
        float send = (sl & 2) ? a2[0] : a2[1];
        float keep = (sl & 2) ? a2[1] : a2[0];
        y = keep + __shfl_xor(send, 2);
    }
    y += __shfl_xor(y, 1);
    return y;
}

// ---------- kernel 1: per-node partials (4 nodes/group, fold, dist-1 pipeline) ----------
__global__ __launch_bounds__(THREADS) void node_partial_kernel(
    const float* __restrict__ nfeats,   // [N, 128]
    const float* __restrict__ W,        // [2, 384]
    float*       __restrict__ pf,       // [N*4] (s0, s1, d0, d1) per node
    int N)
{
    const int sl   = threadIdx.x & 31;
    const int gib  = threadIdx.x >> 5;
    const int g0   = blockIdx.x * GPB + gib;
    const int ngrp = gridDim.x * GPB;
    const int nstep = ngrp * 4;

    const float4 w0s = *reinterpret_cast<const float4*>(W +   0 + 4 * sl);
    const float4 w1s = *reinterpret_cast<const float4*>(W + 384 + 4 * sl);
    const float4 w0d = *reinterpret_cast<const float4*>(W + 128 + 4 * sl);
    const float4 w1d = *reinterpret_cast<const float4*>(W + 384 + 128 + 4 * sl);

    int n = g0 * 4;
    if (n + 3 >= N) return;

    f32x4 h[4];
    #pragma unroll
    for (int j = 0; j < 4; ++j)
        h[j] = __builtin_nontemporal_load(
            reinterpret_cast<const f32x4*>(nfeats + (size_t)(n + j) * D + 4 * sl));

    while (n + 3 < N) {
        // chains c = j*4 + k  (j = node 0..3, k = comp s0,s1,d0,d1)
        float v[16];
        #pragma unroll
        for (int j = 0; j < 4; ++j) {
            v[j*4+0] = h[j].x * w0s.x + h[j].y * w0s.y + h[j].z * w0s.z + h[j].w * w0s.w;
            v[j*4+1] = h[j].x * w1s.x + h[j].y * w1s.y + h[j].z * w1s.z + h[j].w * w1s.w;
            v[j*4+2] = h[j].x * w0d.x + h[j].y * w0d.y + h[j].z * w0d.z + h[j].w * w0d.w;
            v[j*4+3] = h[j].x * w1d.x + h[j].y * w1d.y + h[j].z * w1d.z + h[j].w * w1d.w;
        }

        const int nn = n + nstep;
        if (nn + 3 < N) {
            #pragma unroll
            for (int j = 0; j < 4; ++j)
                h[j] = __builtin_nontemporal_load(
                    reinterpret_cast<const f32x4*>(nfeats + (size_t)(nn + j) * D + 4 * sl));
        }

        const float y = fold16(v, sl);
        // even lane sl holds chain c = sl>>1; pf[4n + c] -> 64 B coalesced,
        // NORMAL store (edge kernel re-reads this table through L2)
        if ((sl & 1) == 0) {
            pf[4 * (size_t)n + (sl >> 1)] = y;
        }
        n = nn;
    }
}

// ---------- kernel 2: distance-2 pipelined edge kernel (8 edges/group) ----------
__global__ __launch_bounds__(THREADS) void edge_kernel(
    const float*  __restrict__ efeats,  // [E, 128]
    const int*    __restrict__ src,     // [E]
    const int*    __restrict__ dst,     // [E]
    const float*  __restrict__ W,       // [2, 384]
    const float*  __restrict__ bias,    // [2]
    const float*  __restrict__ pf,      // [N*4]
    float*        __restrict__ out,     // [E, 2]
    int E)
{
    const int sl   = threadIdx.x & 31;
    const int gib  = threadIdx.x >> 5;
    const int g0   = blockIdx.x * GPB + gib;
    const int ngrp = gridDim.x * GPB;
    const int step = ngrp * 8;

    const float4 w0e = *reinterpret_cast<const float4*>(W + 256 + 4 * sl);
    const float4 w1e = *reinterpret_cast<const float4*>(W + 384 + 256 + 4 * sl);

    const bool wr   = (sl & 1) == 0;
    const int  myj  = sl >> 2;          // writer's edge within the 8-batch
    const int  myo  = (sl >> 1) & 1;    // writer's output index
    const float myb = myo ? bias[1] : bias[0];

    int e = g0 * 8;
    if (e + 7 >= E) return;

    // ---- prologue: fill both pipeline stages ----
    f32x4 heA[8], heB[8];
    int sA = 0, dA = 0, sB = 0, dB = 0;

    load_batch(heA, efeats, e, sl);
    if (wr) { sA = src[e + myj]; dA = dst[e + myj]; }
    if (e + step + 7 < E) {
        load_batch(heB, efeats, e + step, sl);
        if (wr) { sB = src[e + step + myj]; dB = dst[e + step + myj]; }
    }

    for (;;) {
        // ---- process batch in A registers (edges e..e+7) ----
        {
            float ps = 0.f, pd = 0.f;
            if (wr) {
                ps = pf[(size_t)sA * 4 + myo];
                pd = pf[(size_t)dA * 4 + 2 + myo];
            }
            float v[16];
            fma_batch(v, heA, w0e, w1e);
            const int ep = e + 2 * step;          // refill A two stages ahead
            if (ep + 7 < E) {
                load_batch(heA, efeats, ep, sl);
                if (wr) { sA = src[ep + myj]; dA = dst[ep + myj]; }
            }
            const float y = fold16(v, sl);
            if (wr)
                __builtin_nontemporal_store(y + ps + pd + myb,
                                            out + 2 * (size_t)e + (sl >> 1));
        }
        e += step;
        if (e + 7 >= E) break;

        // ---- process batch in B registers (edges e..e+7) ----
        {
            float ps = 0.f, pd = 0.f;
            if (wr) {
                ps = pf[(size_t)sB * 4 + myo];
                pd = pf[(size_t)dB * 4 + 2 + myo];
            }
            float v[16];
            fma_batch(v, heB, w0e, w1e);
            const int ep = e + 2 * step;          // refill B two stages ahead
            if (ep + 7 < E) {
                load_batch(heB, efeats, ep, sl);
                if (wr) { sB = src[ep + myj]; dB = dst[ep + myj]; }
            }
            const float y = fold16(v, sl);
            if (wr)
                __builtin_nontemporal_store(y + ps + pd + myb,
                                            out + 2 * (size_t)e + (sl >> 1));
        }
        e += step;
        if (e + 7 >= E) break;
    }
}

// ---------- fallback: single-kernel (if ws too small) ----------
__global__ __launch_bounds__(THREADS) void mlp_pred_fused_kernel(
    const float* __restrict__ nfeats, const float* __restrict__ efeats,
    const int* __restrict__ src, const int* __restrict__ dst,
    const float* __restrict__ W, const float* __restrict__ bias,
    float* __restrict__ out, int E)
{
    const int sl = threadIdx.x & 31;
    const int gib = threadIdx.x >> 5;
    const int g0 = blockIdx.x * GPB + gib;
    const int ngrp = gridDim.x * GPB;

    const float4 w0s = *reinterpret_cast<const float4*>(W +   0 + 4 * sl);
    const float4 w0d = *reinterpret_cast<const float4*>(W + 128 + 4 * sl);
    const float4 w0e = *reinterpret_cast<const float4*>(W + 256 + 4 * sl);
    const float4 w1s = *reinterpret_cast<const float4*>(W + 384 +   0 + 4 * sl);
    const float4 w1d = *reinterpret_cast<const float4*>(W + 384 + 128 + 4 * sl);
    const float4 w1e = *reinterpret_cast<const float4*>(W + 384 + 256 + 4 * sl);
    const float b0 = bias[0];
    const float b1 = bias[1];

    for (int e = g0; e < E; e += ngrp) {
        const int si = src[e];
        const int di = dst[e];
        const float4 hs = *reinterpret_cast<const float4*>(nfeats + (size_t)si * D + 4 * sl);
        const float4 hd = *reinterpret_cast<const float4*>(nfeats + (size_t)di * D + 4 * sl);
        const float4 he = *reinterpret_cast<const float4*>(efeats + (size_t)e  * D + 4 * sl);

        float a0 = hs.x * w0s.x + hs.y * w0s.y + hs.z * w0s.z + hs.w * w0s.w;
        a0 += hd.x * w0d.x + hd.y * w0d.y + hd.z * w0d.z + hd.w * w0d.w;
        a0 += he.x * w0e.x + he.y * w0e.y + he.z * w0e.z + he.w * w0e.w;
        float a1 = hs.x * w1s.x + hs.y * w1s.y + hs.z * w1s.z + hs.w * w1s.w;
        a1 += hd.x * w1d.x + hd.y * w1d.y + hd.z * w1d.z + hd.w * w1d.w;
        a1 += he.x * w1e.x + he.y * w1e.y + he.z * w1e.z + he.w * w1e.w;

        #pragma unroll
        for (int off = 16; off; off >>= 1) {
            a0 += __shfl_xor(a0, off);
            a1 += __shfl_xor(a1, off);
        }
        if (sl == 0)
            *reinterpret_cast<float2*>(out + 2 * (size_t)e) = make_float2(a0 + b0, a1 + b1);
    }
}

extern "C" void kernel_launch(void* const* d_in, const int* in_sizes, int n_in,
                              void* d_out, int out_size, void* d_ws, size_t ws_size,
                              hipStream_t stream) {
    const float* nfeats = (const float*)d_in[0];
    const float* efeats = (const float*)d_in[1];
    const int*   src    = (const int*)d_in[2];
    const int*   dst    = (const int*)d_in[3];
    const float* W      = (const float*)d_in[4];
    const float* bias   = (const float*)d_in[5];
    float*       out    = (float*)d_out;

    const int E = in_sizes[2];
    const int N = in_sizes[0] / D;

    const size_t p_bytes = (size_t)N * 4 * sizeof(float);

    if (ws_size >= p_bytes && (E & 7) == 0 && (N & 3) == 0) {
        float* pf = (float*)d_ws;

        int groups1 = N / 4;
        int blocks1 = (groups1 + GPB - 1) / GPB;
        if (blocks1 > 2048) blocks1 = 2048;
        node_partial_kernel<<<blocks1, THREADS, 0, stream>>>(nfeats, W, pf, N);

        int groups2 = E / 8;
        int blocks2 = (groups2 + GPB - 1) / GPB;
        if (blocks2 > 2048) blocks2 = 2048;   // back to round-8 grid (A/B isolate)
        edge_kernel<<<blocks2, THREADS, 0, stream>>>(efeats, src, dst, W, bias, pf, out, E);
    } else {
        int blocks = (E + GPB - 1) / GPB;
        if (blocks > 2048) blocks = 2048;
        mlp_pred_fused_kernel<<<blocks, THREADS, 0, stream>>>(nfeats, efeats, src, dst, W, bias, out, E);
    }
}